// Round 2
// baseline (2846.637 us; speedup 1.0000x reference)
//
#include <hip/hip_runtime.h>

typedef unsigned short u16;
typedef unsigned int u32;
typedef unsigned long long u64;

#define NB 8
#define NPTS 4096
#define MSEL 2048
#define NCENT (NB*MSEL)
#define KNBR 64
#define FEAT 64
#define FIN 67
#define HH 64
#define FOUT 128
#define CAND_CAP 192

#define KP1 96     // layer-1 K padded to 3x32
#define SA 104     // feat A-buffer row stride (bf16 elems)
#define S2 72      // h1/h2 row stride

typedef __attribute__((ext_vector_type(8))) short short8;
typedef __attribute__((ext_vector_type(4))) float f32x4;

__device__ __forceinline__ float bf2f(u16 u) {
    union { u32 i; float f; } v; v.i = ((u32)u) << 16; return v.f;
}
__device__ __forceinline__ u16 f2bf(float f) {
    union { float f; u32 i; } v; v.f = f;
    u32 x = v.i;
    x += 0x7fffu + ((x >> 16) & 1u);
    return (u16)(x >> 16);
}
__device__ __forceinline__ void splitbf(float a, u16& hi, u16& lo) {
    u16 h = f2bf(a);
    hi = h;
    lo = f2bf(__fsub_rn(a, bf2f(h)));
}

// ---------------------------------------------------------------------------
// DPP wave-64 reductions (verified r7-r13; byte-identical to the 1618us r13).
// ---------------------------------------------------------------------------
__device__ __forceinline__ int wave_max_i(int v) {
    int u;
    u = __builtin_amdgcn_update_dpp(v, v, 0x111, 0xf, 0xf, false); v = max(v, u);
    u = __builtin_amdgcn_update_dpp(v, v, 0x112, 0xf, 0xf, false); v = max(v, u);
    u = __builtin_amdgcn_update_dpp(v, v, 0x114, 0xf, 0xf, false); v = max(v, u);
    u = __builtin_amdgcn_update_dpp(v, v, 0x118, 0xf, 0xf, false); v = max(v, u);
    u = __builtin_amdgcn_update_dpp(v, v, 0x142, 0xf, 0xf, false); v = max(v, u);
    u = __builtin_amdgcn_update_dpp(v, v, 0x143, 0xf, 0xf, false); v = max(v, u);
    return __builtin_amdgcn_readlane(v, 63);
}
__device__ __forceinline__ int wave_min_i(int v) {
    int u;
    u = __builtin_amdgcn_update_dpp(v, v, 0x111, 0xf, 0xf, false); v = min(v, u);
    u = __builtin_amdgcn_update_dpp(v, v, 0x112, 0xf, 0xf, false); v = min(v, u);
    u = __builtin_amdgcn_update_dpp(v, v, 0x114, 0xf, 0xf, false); v = min(v, u);
    u = __builtin_amdgcn_update_dpp(v, v, 0x118, 0xf, 0xf, false); v = min(v, u);
    u = __builtin_amdgcn_update_dpp(v, v, 0x142, 0xf, 0xf, false); v = min(v, u);
    u = __builtin_amdgcn_update_dpp(v, v, 0x143, 0xf, 0xf, false); v = min(v, u);
    return __builtin_amdgcn_readlane(v, 63);
}

// ---------------------------------------------------------------------------
// Kernel 1: exact FPS with spatial pruning. r13 chassis (256 thr, 4 waves,
// int two-pass DPP reduce, serial 4-entry merge) + exact bucket skipping:
//   - counting-sort points into 8x8x8 grid cells; thread t owns 16
//     spatially contiguous points + tight AABB
//   - skip bucket iff lb2*(1-1e-5) >= bv  (lb = AABB lower bound to c).
//     Conservative: skip => every computed d2 > md[j] => fminf identity =>
//     stored md and bucket argmax stay EXACT. Rounding slack 1e-5 >> the
//     ~3e-7 relative error of the d2/lb2 float evaluations.
//   - active buckets use the r13-verbatim exact arithmetic; bucket argmax
//     rebuilt with (max value, min ORIGINAL index) u64 keys => global
//     selection sequence is bit-identical to r13/reference (partition-
//     independent (max, min-idx) semantics at every level).
// ---------------------------------------------------------------------------
__global__ __launch_bounds__(256) void fps_kernel(const float* __restrict__ pos,
        int* __restrict__ sel, float* __restrict__ pos_out,
        float* __restrict__ batch_out) {
    __shared__ float px[NPTS], py[NPTS], pz[NPTS];
    __shared__ int hist[MSEL];
    __shared__ int sidx[NPTS];
    __shared__ u32 cellc[512];
    __shared__ int4  sA[2][4];    // {M, I, xbits, ybits} per wave
    __shared__ float sZ[2][4];
    const int b = blockIdx.x, t = threadIdx.x;
    const int wid = t >> 6;
    const float* pb = pos + (long)b * NPTS * 3;

    for (int i = t; i < NPTS; i += 256) {
        px[i] = pb[i*3+0]; py[i] = pb[i*3+1]; pz[i] = pb[i*3+2];
    }
    for (int i = t; i < 512; i += 256) cellc[i] = 0;
    __syncthreads();

    // ---- counting sort by grid cell (one-time; order within cell is
    // nondeterministic but selection is partition-independent)
    for (int i = t; i < NPTS; i += 256) {
        int qx = (int)(px[i] * 8.0f); qx = qx < 0 ? 0 : (qx > 7 ? 7 : qx);
        int qy = (int)(py[i] * 8.0f); qy = qy < 0 ? 0 : (qy > 7 ? 7 : qy);
        int qz = (int)(pz[i] * 8.0f); qz = qz < 0 ? 0 : (qz > 7 ? 7 : qz);
        atomicAdd(&cellc[(qz<<6)|(qy<<3)|qx], 1u);
    }
    __syncthreads();
    if (t == 0) {
        u32 run = 0;
        for (int c2 = 0; c2 < 512; ++c2) { u32 v = cellc[c2]; cellc[c2] = run; run += v; }
    }
    __syncthreads();
    for (int i = t; i < NPTS; i += 256) {
        int qx = (int)(px[i] * 8.0f); qx = qx < 0 ? 0 : (qx > 7 ? 7 : qx);
        int qy = (int)(py[i] * 8.0f); qy = qy < 0 ? 0 : (qy > 7 ? 7 : qy);
        int qz = (int)(pz[i] * 8.0f); qz = qz < 0 ? 0 : (qz > 7 ? 7 : qz);
        u32 slot = atomicAdd(&cellc[(qz<<6)|(qy<<3)|qx], 1u);
        sidx[slot] = i;
    }
    __syncthreads();

    float rx[16], ry[16], rz[16], md[16];
    int idx[16];
    #pragma unroll
    for (int j = 0; j < 16; ++j) {
        int g = sidx[t*16 + j];
        idx[j] = g;
        rx[j] = px[g]; ry[j] = py[g]; rz[j] = pz[g];
        md[j] = __builtin_inff();
    }
    float lox = rx[0], hix = rx[0], loy = ry[0], hiy = ry[0], loz = rz[0], hiz = rz[0];
    #pragma unroll
    for (int j = 1; j < 16; ++j) {
        lox = fminf(lox, rx[j]); hix = fmaxf(hix, rx[j]);
        loy = fminf(loy, ry[j]); hiy = fmaxf(hiy, ry[j]);
        loz = fminf(loz, rz[j]); hiz = fmaxf(hiz, rz[j]);
    }

    float bv, bx, by, bz; int bi;
    auto rebuild = [&]() {
        // bucket argmax: (max md, min original index) via packed u64 keys.
        // md >= 0 so float order == unsigned int order on the high word.
        u64 kk[16];
        #pragma unroll
        for (int j = 0; j < 16; ++j)
            kk[j] = (((u64)__float_as_uint(md[j])) << 32) | (u32)(4095 - idx[j]);
        #pragma unroll
        for (int st = 1; st < 16; st <<= 1) {
            #pragma unroll
            for (int j0 = 0; j0 < 16; j0 += 2*st) {
                u64 a = kk[j0], c2 = kk[j0+st];
                kk[j0] = (c2 > a) ? c2 : a;
            }
        }
        bv = __uint_as_float((u32)(kk[0] >> 32));
        bi = 4095 - (int)((u32)kk[0]);
        #pragma unroll
        for (int j = 0; j < 16; ++j)
            if (idx[j] == bi) { bx = rx[j]; by = ry[j]; bz = rz[j]; }
    };
    rebuild();

    int cur = 0;
    float cx = px[0], cy = py[0], cz = pz[0];
    for (int s = 0; s < MSEL; ++s) {
        const int p = s & 1;
        if (t == 0) hist[s] = cur;
        // conservative AABB lower bound on d2 from c to any point in bucket
        float ax = fmaxf(fmaxf(lox - cx, cx - hix), 0.0f);
        float ay = fmaxf(fmaxf(loy - cy, cy - hiy), 0.0f);
        float az = fmaxf(fmaxf(loz - cz, cz - hiz), 0.0f);
        float lb2 = ax*ax + ay*ay + az*az;
        if (lb2 * 0.99999f < bv) {
            bool ch = false;
            #pragma unroll
            for (int j = 0; j < 16; ++j) {
                float dx = __fsub_rn(rx[j], cx);
                float dy = __fsub_rn(ry[j], cy);
                float dz = __fsub_rn(rz[j], cz);
                float d  = __fadd_rn(__fadd_rn(__fmul_rn(dx,dx), __fmul_rn(dy,dy)),
                                     __fmul_rn(dz,dz));
                ch |= (d < md[j]);
                md[j] = fminf(md[j], d);
            }
            if (ch) rebuild();
        }
        const int fb = (int)__float_as_uint(bv);   // bv >= 0 -> int-ordered
        const int Mw = wave_max_i(fb);
        const int cnd = (fb == Mw) ? bi : 0x7fffffff;
        const int Iw = wave_min_i(cnd);            // wave argmax, min orig idx
        if (bi == Iw) {                            // unique owner in wave
            sA[p][wid] = make_int4(Mw, Iw, __float_as_int(bx), __float_as_int(by));
            sZ[p][wid] = bz;
        }
        __syncthreads();
        int4 v0 = sA[p][0];
        int M = v0.x, I = v0.y;
        float nx = __int_as_float(v0.z), ny = __int_as_float(v0.w), nz = sZ[p][0];
        #pragma unroll
        for (int w2 = 1; w2 < 4; ++w2) {
            int4 vw = sA[p][w2];
            if (vw.x > M || (vw.x == M && vw.y < I)) {
                M = vw.x; I = vw.y;
                nx = __int_as_float(vw.z); ny = __int_as_float(vw.w);
                nz = sZ[p][w2];
            }
        }
        cur = I; cx = nx; cy = ny; cz = nz;
    }
    __syncthreads();
    for (int g = t; g < MSEL; g += 256) {
        int i = hist[g];
        int o = b * MSEL + g;
        sel[o] = i;
        pos_out[o*3+0] = px[i]; pos_out[o*3+1] = py[i]; pos_out[o*3+2] = pz[i];
        batch_out[o] = (float)b;
    }
}

// ---------------------------------------------------------------------------
// Kernel 1.5: weight pre-transform (unchanged, verified).
// ---------------------------------------------------------------------------
__global__ __launch_bounds__(256) void wcvt_kernel(const float* __restrict__ W1,
        const float* __restrict__ W2, const float* __restrict__ W3,
        u16* __restrict__ w1h, u16* __restrict__ w1l,
        u16* __restrict__ w2h, u16* __restrict__ w2l,
        u16* __restrict__ w3h, u16* __restrict__ w3l) {
    int t = blockIdx.x * 256 + threadIdx.x;
    if (t < 64*KP1) {
        int n = t / KP1, k = t % KP1;
        u16 h, l; splitbf((k < FIN) ? W1[(long)k*HH + n] : 0.0f, h, l);
        w1h[t] = h; w1l[t] = l;
    }
    if (t < 64*64) {
        int n = t / 64, k = t % 64;
        u16 h, l; splitbf(W2[(long)k*HH + n], h, l);
        w2h[t] = h; w2l[t] = l;
    }
    if (t < 128*64) {
        int n = t / 64, k = t % 64;
        u16 h, l; splitbf(W3[(long)k*FOUT + n], h, l);
        w3h[t] = h; w3l[t] = l;
    }
}

// ---------------------------------------------------------------------------
// Kernel 2: fused radius + PointNetConv + max-pool, COLUMN-PARTITIONED waves.
// (unchanged, verified; absmax tripwire: exactly 0.015625)
// ---------------------------------------------------------------------------
__global__ __launch_bounds__(256) void conv_kernel(const float* __restrict__ x,
        const float* __restrict__ pos, const int* __restrict__ sel,
        const u16* __restrict__ w1h, const u16* __restrict__ w1l,
        const u16* __restrict__ w2h, const u16* __restrict__ w2l,
        const u16* __restrict__ w3h, const u16* __restrict__ w3l,
        const float* __restrict__ b1, const float* __restrict__ b2,
        const float* __restrict__ b3, float* __restrict__ xout) {
    __shared__ __align__(16) u16 fAh[64*SA], fAl[64*SA];   // feat, then h2 (stride S2)
    __shared__ __align__(16) u16 h1h[64*S2], h1l[64*S2];
    __shared__ float cdv[CAND_CAP];
    __shared__ int   cixv[CAND_CAP];
    __shared__ int   snbr[KNBR];
    __shared__ int   sc[2];
    const int c = blockIdx.x, t = threadIdx.x;
    const int b = c >> 11;
    const int lane = t & 63, w = t >> 6;
    const int colc = lane & 15;
    const float* pb = pos + (long)b * NPTS * 3;
    const int j0 = sel[c];
    const float qx = pb[j0*3+0], qy = pb[j0*3+1], qz = pb[j0*3+2];

    const int nw = w*16 + colc;            // this wave's column (layers 1-2)
    const float bias1 = b1[nw];
    const float bias2 = b2[nw];
    const float bias3[2] = { b3[(2*w+0)*16 + colc], b3[(2*w+1)*16 + colc] };

    if (t == 0) { sc[0] = 0; sc[1] = 0; }
    __syncthreads();

    // ---- radius gather (bit-exact; verified r4-r13)
    const float R2 = (float)(0.15 * 0.15);
    for (int it = 0; it < NPTS/256; ++it) {
        int i = t + 256*it;
        float dx = __fsub_rn(qx, pb[i*3+0]);
        float dy = __fsub_rn(qy, pb[i*3+1]);
        float dz = __fsub_rn(qz, pb[i*3+2]);
        float d2 = __fadd_rn(__fadd_rn(__fmul_rn(dx,dx), __fmul_rn(dy,dy)),
                             __fmul_rn(dz,dz));
        if (d2 <= R2) {
            int slot = atomicAdd(&sc[0], 1);
            if (slot < CAND_CAP) { cdv[slot] = d2; cixv[slot] = i; }
        }
    }
    __syncthreads();
    int C = sc[0]; if (C > CAND_CAP) C = CAND_CAP;
    int cnt;
    if (C <= KNBR) {
        for (int e = t; e < C; e += 256) snbr[e] = cixv[e];
        cnt = C;
    } else {
        for (int e = t; e < C; e += 256) {
            float de = cdv[e]; int ie = cixv[e];
            int rank = 0;
            for (int f = 0; f < C; ++f) {
                float df = cdv[f]; int jf = cixv[f];
                rank += (df < de || (df == de && jf < ie)) ? 1 : 0;
            }
            if (rank < KNBR) {
                int slot = atomicAdd(&sc[1], 1);
                snbr[slot] = ie;
            }
        }
        cnt = KNBR;
    }
    __syncthreads();

    // ---- stage features (4 threads/row); zero K-pad cols 67..99
    const int kk = t >> 2, sub = t & 3;
    if (kk < cnt) {
        int j = snbr[kk];
        const float4* xr4 = (const float4*)(x + ((long)b*NPTS + j) * FEAT);
        #pragma unroll
        for (int i = 0; i < 4; ++i) {
            int ci = sub*4 + i;
            float4 v = xr4[ci];
            u16 h0,l0,h1_,l1_,h2_,l2_,h3_,l3_;
            splitbf(v.x, h0, l0); splitbf(v.y, h1_, l1_);
            splitbf(v.z, h2_, l2_); splitbf(v.w, h3_, l3_);
            int o = kk*SA + ci*4;
            fAh[o+0]=h0; fAh[o+1]=h1_; fAh[o+2]=h2_; fAh[o+3]=h3_;
            fAl[o+0]=l0; fAl[o+1]=l1_; fAl[o+2]=l2_; fAl[o+3]=l3_;
        }
        if (sub < 3) {
            float qv = (sub == 0) ? qx : ((sub == 1) ? qy : qz);
            u16 h, l; splitbf(__fsub_rn(pb[j*3+sub], qv), h, l);
            fAh[kk*SA + 64 + sub] = h; fAl[kk*SA + 64 + sub] = l;
        } else {
            fAh[kk*SA + 67] = 0; fAl[kk*SA + 67] = 0;
        }
        u32* zh = (u32*)&fAh[kk*SA + 68];
        u32* zl = (u32*)&fAl[kk*SA + 68];
        #pragma unroll
        for (int i2 = 0; i2 < 4; ++i2) { zh[sub + 4*i2] = 0; zl[sub + 4*i2] = 0; }
    }
    __syncthreads();   // layer 1 reads ALL rows -> full barrier

    const int mL = lane & 15;              // A-row within a 16-row tile
    const int kq = (lane >> 4) * 8;
    const int rgrp = (lane >> 4) * 4;

    // ---- B-fragment loads: this wave's column stripe only (18 KB/wave)
    short8 B1h[3], B1l[3], B2h[2], B2l[2], B3h[2][2], B3l[2][2];
    #pragma unroll
    for (int i = 0; i < 3; ++i) {
        B1h[i] = *(const short8*)&w1h[nw*KP1 + i*32 + kq];
        B1l[i] = *(const short8*)&w1l[nw*KP1 + i*32 + kq];
    }
    #pragma unroll
    for (int i = 0; i < 2; ++i) {
        B2h[i] = *(const short8*)&w2h[nw*64 + i*32 + kq];
        B2l[i] = *(const short8*)&w2l[nw*64 + i*32 + kq];
    }

    // ---- layer 1: 96(67) -> 64, all 4 row-tiles, cols nw
    #pragma unroll
    for (int rt = 0; rt < 4; ++rt) {
        short8 ah[3], al[3];
        #pragma unroll
        for (int i = 0; i < 3; ++i) {
            ah[i] = *(const short8*)&fAh[(rt*16 + mL)*SA + i*32 + kq];
            al[i] = *(const short8*)&fAl[(rt*16 + mL)*SA + i*32 + kq];
        }
        f32x4 acc = {bias1, bias1, bias1, bias1};
        #pragma unroll
        for (int i = 0; i < 3; ++i)
            acc = __builtin_amdgcn_mfma_f32_16x16x32_bf16(ah[i], B1h[i], acc, 0,0,0);
        #pragma unroll
        for (int i = 0; i < 3; ++i)
            acc = __builtin_amdgcn_mfma_f32_16x16x32_bf16(ah[i], B1l[i], acc, 0,0,0);
        #pragma unroll
        for (int i = 0; i < 3; ++i)
            acc = __builtin_amdgcn_mfma_f32_16x16x32_bf16(al[i], B1h[i], acc, 0,0,0);
        #pragma unroll
        for (int r = 0; r < 4; ++r) {
            u16 h, l; splitbf(fmaxf(acc[r], 0.0f), h, l);
            int mr = rt*16 + rgrp + r;
            h1h[mr*S2 + nw] = h; h1l[mr*S2 + nw] = l;
        }
    }
    // prefetch layer-3 B while layer-1 results drain
    #pragma unroll
    for (int j = 0; j < 2; ++j) {
        int n3 = (2*w + j)*16 + colc;
        #pragma unroll
        for (int i = 0; i < 2; ++i) {
            B3h[j][i] = *(const short8*)&w3h[n3*64 + i*32 + kq];
            B3l[j][i] = *(const short8*)&w3l[n3*64 + i*32 + kq];
        }
    }
    __syncthreads();

    // ---- layer 2: 64 -> 64 (h2 overwrites fA, stride S2)
    #pragma unroll
    for (int rt = 0; rt < 4; ++rt) {
        short8 ah[2], al[2];
        #pragma unroll
        for (int i = 0; i < 2; ++i) {
            ah[i] = *(const short8*)&h1h[(rt*16 + mL)*S2 + i*32 + kq];
            al[i] = *(const short8*)&h1l[(rt*16 + mL)*S2 + i*32 + kq];
        }
        f32x4 acc = {bias2, bias2, bias2, bias2};
        #pragma unroll
        for (int i = 0; i < 2; ++i)
            acc = __builtin_amdgcn_mfma_f32_16x16x32_bf16(ah[i], B2h[i], acc, 0,0,0);
        #pragma unroll
        for (int i = 0; i < 2; ++i)
            acc = __builtin_amdgcn_mfma_f32_16x16x32_bf16(ah[i], B2l[i], acc, 0,0,0);
        #pragma unroll
        for (int i = 0; i < 2; ++i)
            acc = __builtin_amdgcn_mfma_f32_16x16x32_bf16(al[i], B2h[i], acc, 0,0,0);
        #pragma unroll
        for (int r = 0; r < 4; ++r) {
            u16 h, l; splitbf(fmaxf(acc[r], 0.0f), h, l);
            int mr = rt*16 + rgrp + r;
            fAh[mr*S2 + nw] = h; fAl[mr*S2 + nw] = l;
        }
    }
    __syncthreads();

    // ---- layer 3: 64 -> 128, 2 col stripes/wave, fused relu + masked pool
    #pragma unroll
    for (int j = 0; j < 2; ++j) {
        const float bb = bias3[j];
        float v = 0.0f;   // relu >= 0 and cnt >= 1 -> 0 is identity
        #pragma unroll
        for (int rt = 0; rt < 4; ++rt) {
            short8 ah[2], al[2];
            #pragma unroll
            for (int i = 0; i < 2; ++i) {
                ah[i] = *(const short8*)&fAh[(rt*16 + mL)*S2 + i*32 + kq];
                al[i] = *(const short8*)&fAl[(rt*16 + mL)*S2 + i*32 + kq];
            }
            f32x4 acc = {bb, bb, bb, bb};
            #pragma unroll
            for (int i = 0; i < 2; ++i)
                acc = __builtin_amdgcn_mfma_f32_16x16x32_bf16(ah[i], B3h[j][i], acc, 0,0,0);
            #pragma unroll
            for (int i = 0; i < 2; ++i)
                acc = __builtin_amdgcn_mfma_f32_16x16x32_bf16(ah[i], B3l[j][i], acc, 0,0,0);
            #pragma unroll
            for (int i = 0; i < 2; ++i)
                acc = __builtin_amdgcn_mfma_f32_16x16x32_bf16(al[i], B3h[j][i], acc, 0,0,0);
            #pragma unroll
            for (int r = 0; r < 4; ++r) {
                int m = rt*16 + rgrp + r;
                float hv = fmaxf(acc[r], 0.0f);
                v = (m < cnt) ? fmaxf(v, hv) : v;
            }
        }
        v = fmaxf(v, __shfl_xor(v, 16, 64));
        v = fmaxf(v, __shfl_xor(v, 32, 64));
        if (lane < 16)
            xout[(long)c*FOUT + (2*w + j)*16 + lane] = v;
    }
}

// ---------------------------------------------------------------------------
extern "C" void kernel_launch(void* const* d_in, const int* in_sizes, int n_in,
                              void* d_out, int out_size, void* d_ws, size_t ws_size,
                              hipStream_t stream) {
    const float* x   = (const float*)d_in[0];
    const float* pos = (const float*)d_in[1];
    const float* W1 = (const float*)d_in[3];
    const float* b1 = (const float*)d_in[4];
    const float* W2 = (const float*)d_in[5];
    const float* b2 = (const float*)d_in[6];
    const float* W3 = (const float*)d_in[7];
    const float* b3 = (const float*)d_in[8];

    float* out       = (float*)d_out;
    float* xout      = out;
    float* pos_out   = out + (long)NCENT * FOUT;
    float* batch_out = pos_out + (long)NCENT * 3;

    int* sel = (int*)d_ws;
    u16* w1h = (u16*)((char*)d_ws + 65536);
    u16* w1l = w1h + 64*KP1;
    u16* w2h = w1l + 64*KP1;
    u16* w2l = w2h + 64*64;
    u16* w3h = w2l + 64*64;
    u16* w3l = w3h + 128*64;

    wcvt_kernel<<<32, 256, 0, stream>>>(W1, W2, W3, w1h, w1l, w2h, w2l, w3h, w3l);
    fps_kernel<<<NB, 256, 0, stream>>>(pos, sel, pos_out, batch_out);
    conv_kernel<<<NCENT, 256, 0, stream>>>(x, pos, sel, w1h, w1l, w2h, w2l,
                                           w3h, w3l, b1, b2, b3, xout);
}

// Round 3
// 2745.600 us; speedup vs baseline: 1.0368x; 1.0368x over previous
//
#include <hip/hip_runtime.h>

typedef unsigned short u16;
typedef unsigned int u32;
typedef unsigned long long u64;

#define NB 8
#define NPTS 4096
#define MSEL 2048
#define NCENT (NB*MSEL)
#define KNBR 64
#define FEAT 64
#define FIN 67
#define HH 64
#define FOUT 128
#define CAND_CAP 192

#define KP1 96     // layer-1 K padded to 3x32
#define SA 104     // feat A-buffer row stride (bf16 elems)
#define S2 72      // h1/h2 row stride

typedef __attribute__((ext_vector_type(8))) short short8;
typedef __attribute__((ext_vector_type(4))) float f32x4;

__device__ __forceinline__ float bf2f(u16 u) {
    union { u32 i; float f; } v; v.i = ((u32)u) << 16; return v.f;
}
__device__ __forceinline__ u16 f2bf(float f) {
    union { float f; u32 i; } v; v.f = f;
    u32 x = v.i;
    x += 0x7fffu + ((x >> 16) & 1u);
    return (u16)(x >> 16);
}
__device__ __forceinline__ void splitbf(float a, u16& hi, u16& lo) {
    u16 h = f2bf(a);
    hi = h;
    lo = f2bf(__fsub_rn(a, bf2f(h)));
}

// ---------------------------------------------------------------------------
// DPP wave-64 reductions (verified r7-r13).
// ---------------------------------------------------------------------------
__device__ __forceinline__ int wave_max_i(int v) {
    int u;
    u = __builtin_amdgcn_update_dpp(v, v, 0x111, 0xf, 0xf, false); v = max(v, u);
    u = __builtin_amdgcn_update_dpp(v, v, 0x112, 0xf, 0xf, false); v = max(v, u);
    u = __builtin_amdgcn_update_dpp(v, v, 0x114, 0xf, 0xf, false); v = max(v, u);
    u = __builtin_amdgcn_update_dpp(v, v, 0x118, 0xf, 0xf, false); v = max(v, u);
    u = __builtin_amdgcn_update_dpp(v, v, 0x142, 0xf, 0xf, false); v = max(v, u);
    u = __builtin_amdgcn_update_dpp(v, v, 0x143, 0xf, 0xf, false); v = max(v, u);
    return __builtin_amdgcn_readlane(v, 63);
}
__device__ __forceinline__ int wave_min_i(int v) {
    int u;
    u = __builtin_amdgcn_update_dpp(v, v, 0x111, 0xf, 0xf, false); v = min(v, u);
    u = __builtin_amdgcn_update_dpp(v, v, 0x112, 0xf, 0xf, false); v = min(v, u);
    u = __builtin_amdgcn_update_dpp(v, v, 0x114, 0xf, 0xf, false); v = min(v, u);
    u = __builtin_amdgcn_update_dpp(v, v, 0x118, 0xf, 0xf, false); v = min(v, u);
    u = __builtin_amdgcn_update_dpp(v, v, 0x142, 0xf, 0xf, false); v = min(v, u);
    u = __builtin_amdgcn_update_dpp(v, v, 0x143, 0xf, 0xf, false); v = min(v, u);
    return __builtin_amdgcn_readlane(v, 63);
}

// ---------------------------------------------------------------------------
// Kernel 1: exact FPS, chunk-granular pruning on the r13 chassis.
//   - counting-sort points by 8x8x8 cell (r2-verified, partition-independent)
//   - wave w, slot sb owns sorted positions [1024w+256sb, +256): a contiguous
//     SPATIAL chunk. Per lane: 4 pts/slot, idx-ascending within the 4-group
//     (5-CE network) so strict-> tracking = min original index on ties.
//   - per-iteration, per slot: AABB lower-bound test (lane tests its own
//     4-pt max sbv; __any over wave == "chunk needs update"). Skip is exact:
//     lb2*0.99999 >= sbv  =>  every computed d > every md in the chunk-part
//     => fminf identity and persistent (sbv,sbc) remain the exact recompute.
//   - active slots rerun the r13-verbatim exact loop with INLINE tracking
//     (no rebuild pass). Wave reduce (gated on any change): int DPP max +
//     ballot fast-path for the min-index tie pass (exact either way).
//   - every iteration lane0 publishes the wave's cached candidate; block
//     merge is r13-verbatim ((max, min-idx) at every level => selection
//     sequence bit-identical to reference; absmax tripwire 0.015625).
// ---------------------------------------------------------------------------
__global__ __launch_bounds__(256) void fps_kernel(const float* __restrict__ pos,
        int* __restrict__ sel, float* __restrict__ pos_out,
        float* __restrict__ batch_out) {
    __shared__ float px[NPTS], py[NPTS], pz[NPTS];
    __shared__ int hist[MSEL];
    __shared__ int sidx[NPTS];
    __shared__ u32 cellc[512];
    __shared__ int4  sA[2][4];    // {M, Icode, xbits, ybits} per wave
    __shared__ float sZ[2][4];
    const int b = blockIdx.x, t = threadIdx.x;
    const int wid = t >> 6, lane = t & 63;
    const float* pb = pos + (long)b * NPTS * 3;

    for (int i = t; i < NPTS; i += 256) {
        px[i] = pb[i*3+0]; py[i] = pb[i*3+1]; pz[i] = pb[i*3+2];
    }
    for (int i = t; i < 512; i += 256) cellc[i] = 0;
    __syncthreads();

    // ---- counting sort by grid cell (one-time; r2-verified)
    for (int i = t; i < NPTS; i += 256) {
        int qx = (int)(px[i] * 8.0f); qx = qx < 0 ? 0 : (qx > 7 ? 7 : qx);
        int qy = (int)(py[i] * 8.0f); qy = qy < 0 ? 0 : (qy > 7 ? 7 : qy);
        int qz = (int)(pz[i] * 8.0f); qz = qz < 0 ? 0 : (qz > 7 ? 7 : qz);
        atomicAdd(&cellc[(qz<<6)|(qy<<3)|qx], 1u);
    }
    __syncthreads();
    if (t == 0) {
        u32 run = 0;
        for (int c2 = 0; c2 < 512; ++c2) { u32 v = cellc[c2]; cellc[c2] = run; run += v; }
    }
    __syncthreads();
    for (int i = t; i < NPTS; i += 256) {
        int qx = (int)(px[i] * 8.0f); qx = qx < 0 ? 0 : (qx > 7 ? 7 : qx);
        int qy = (int)(py[i] * 8.0f); qy = qy < 0 ? 0 : (qy > 7 ? 7 : qy);
        int qz = (int)(pz[i] * 8.0f); qz = qz < 0 ? 0 : (qz > 7 ? 7 : qz);
        u32 slot = atomicAdd(&cellc[(qz<<6)|(qy<<3)|qx], 1u);
        sidx[slot] = i;
    }
    __syncthreads();

    // ---- per-lane ownership: slot sb -> 4 pts of chunk [1024w+256sb, +256)
    int idx[16];
    #pragma unroll
    for (int sb = 0; sb < 4; ++sb) {
        #pragma unroll
        for (int q = 0; q < 4; ++q)
            idx[sb*4+q] = sidx[1024*wid + 256*sb + 4*lane + q];
        int i0 = idx[sb*4], i1 = idx[sb*4+1], i2 = idx[sb*4+2], i3 = idx[sb*4+3], tq;
        if (i0 > i1) { tq = i0; i0 = i1; i1 = tq; }
        if (i2 > i3) { tq = i2; i2 = i3; i3 = tq; }
        if (i0 > i2) { tq = i0; i0 = i2; i2 = tq; }
        if (i1 > i3) { tq = i1; i1 = i3; i3 = tq; }
        if (i1 > i2) { tq = i1; i1 = i2; i2 = tq; }
        idx[sb*4] = i0; idx[sb*4+1] = i1; idx[sb*4+2] = i2; idx[sb*4+3] = i3;
    }
    float rx[16], ry[16], rz[16], md[16]; int code[16];
    #pragma unroll
    for (int j = 0; j < 16; ++j) {
        int g = idx[j];
        rx[j] = px[g]; ry[j] = py[g]; rz[j] = pz[g];
        md[j] = __builtin_inff();
        code[j] = (g << 4) | j;
    }
    // persistent per-slot candidates + wave-uniform chunk AABBs
    float sbv[4]; int sbc[4];
    float clox[4], chix[4], cloy[4], chiy[4], cloz[4], chiz[4];
    #pragma unroll
    for (int sb = 0; sb < 4; ++sb) {
        sbv[sb] = __builtin_inff(); sbc[sb] = code[sb*4];
        float lx = fminf(fminf(rx[sb*4], rx[sb*4+1]), fminf(rx[sb*4+2], rx[sb*4+3]));
        float hx = fmaxf(fmaxf(rx[sb*4], rx[sb*4+1]), fmaxf(rx[sb*4+2], rx[sb*4+3]));
        float ly = fminf(fminf(ry[sb*4], ry[sb*4+1]), fminf(ry[sb*4+2], ry[sb*4+3]));
        float hy = fmaxf(fmaxf(ry[sb*4], ry[sb*4+1]), fmaxf(ry[sb*4+2], ry[sb*4+3]));
        float lz = fminf(fminf(rz[sb*4], rz[sb*4+1]), fminf(rz[sb*4+2], rz[sb*4+3]));
        float hz = fmaxf(fmaxf(rz[sb*4], rz[sb*4+1]), fmaxf(rz[sb*4+2], rz[sb*4+3]));
        // coords in [0,1): float bits are int-monotone
        clox[sb] = __int_as_float(wave_min_i(__float_as_int(lx)));
        chix[sb] = __int_as_float(wave_max_i(__float_as_int(hx)));
        cloy[sb] = __int_as_float(wave_min_i(__float_as_int(ly)));
        chiy[sb] = __int_as_float(wave_max_i(__float_as_int(hy)));
        cloz[sb] = __int_as_float(wave_min_i(__float_as_int(lz)));
        chiz[sb] = __int_as_float(wave_max_i(__float_as_int(hz)));
    }
    int cMw = 0, cIw = 0; float ccx = 0.0f, ccy = 0.0f, ccz = 0.0f;

    int cur = 0;
    float cx = px[0], cy = py[0], cz = pz[0];
    for (int s = 0; s < MSEL; ++s) {
        const int p = s & 1;
        if (t == 0) hist[s] = cur;
        bool ch = false;
        #pragma unroll
        for (int sb = 0; sb < 4; ++sb) {
            float ax = fmaxf(fmaxf(__fsub_rn(clox[sb], cx), __fsub_rn(cx, chix[sb])), 0.0f);
            float ay = fmaxf(fmaxf(__fsub_rn(cloy[sb], cy), __fsub_rn(cy, chiy[sb])), 0.0f);
            float az = fmaxf(fmaxf(__fsub_rn(cloz[sb], cz), __fsub_rn(cz, chiz[sb])), 0.0f);
            float lb2 = ax*ax + ay*ay + az*az;
            bool act = (lb2 * 0.99999f < sbv[sb]);
            if (__any(act)) {
                float nv = -1.0f; int nc = 0;
                #pragma unroll
                for (int q = 0; q < 4; ++q) {
                    const int j = sb*4 + q;
                    float dx = __fsub_rn(rx[j], cx);
                    float dy = __fsub_rn(ry[j], cy);
                    float dz = __fsub_rn(rz[j], cz);
                    float d  = __fadd_rn(__fadd_rn(__fmul_rn(dx,dx), __fmul_rn(dy,dy)),
                                         __fmul_rn(dz,dz));
                    ch |= (d < md[j]);
                    float m = fminf(md[j], d);
                    md[j] = m;
                    bool g = (m > nv);
                    nv = g ? m : nv;
                    nc = g ? code[j] : nc;
                }
                sbv[sb] = nv; sbc[sb] = nc;
            }
        }
        if (__any(ch)) {
            // lane combine: (max val, min code) over 4 slots
            bool g01 = (sbv[1] > sbv[0]) || ((sbv[1] == sbv[0]) && (sbc[1] < sbc[0]));
            float vA = g01 ? sbv[1] : sbv[0]; int cA = g01 ? sbc[1] : sbc[0];
            bool g23 = (sbv[3] > sbv[2]) || ((sbv[3] == sbv[2]) && (sbc[3] < sbc[2]));
            float vB = g23 ? sbv[3] : sbv[2]; int cB = g23 ? sbc[3] : sbc[2];
            bool gf = (vB > vA) || ((vB == vA) && (cB < cA));
            float bvL = gf ? vB : vA; int bcL = gf ? cB : cA;
            int fb = (int)__float_as_uint(bvL);
            int Mw = wave_max_i(fb);
            u64 mk = __ballot(fb == Mw);
            int Iw;
            if (__popcll(mk) == 1) {
                Iw = __builtin_amdgcn_readlane(bcL, (int)__builtin_ctzll(mk));
            } else {
                int cnd = (fb == Mw) ? bcL : 0x7fffffff;
                Iw = wave_min_i(cnd);
                mk = __ballot((fb == Mw) && (bcL == Iw));
            }
            int src = (int)__builtin_ctzll(mk);
            int jj = Iw & 15;                 // uniform; owner's point slot
            cMw = Mw; cIw = Iw;
            ccx = __int_as_float(__builtin_amdgcn_readlane(__float_as_int(rx[jj]), src));
            ccy = __int_as_float(__builtin_amdgcn_readlane(__float_as_int(ry[jj]), src));
            ccz = __int_as_float(__builtin_amdgcn_readlane(__float_as_int(rz[jj]), src));
        }
        if (lane == 0) {
            sA[p][wid] = make_int4(cMw, cIw, __float_as_int(ccx), __float_as_int(ccy));
            sZ[p][wid] = ccz;
        }
        __syncthreads();
        int4 v0 = sA[p][0];
        int M = v0.x, I = v0.y;
        float nx = __int_as_float(v0.z), ny = __int_as_float(v0.w), nz = sZ[p][0];
        #pragma unroll
        for (int w2 = 1; w2 < 4; ++w2) {
            int4 vw = sA[p][w2];
            if (vw.x > M || (vw.x == M && vw.y < I)) {
                M = vw.x; I = vw.y;
                nx = __int_as_float(vw.z); ny = __int_as_float(vw.w);
                nz = sZ[p][w2];
            }
        }
        cur = I >> 4; cx = nx; cy = ny; cz = nz;
    }
    __syncthreads();
    for (int g = t; g < MSEL; g += 256) {
        int i = hist[g];
        int o = b * MSEL + g;
        sel[o] = i;
        pos_out[o*3+0] = px[i]; pos_out[o*3+1] = py[i]; pos_out[o*3+2] = pz[i];
        batch_out[o] = (float)b;
    }
}

// ---------------------------------------------------------------------------
// Kernel 1.5: weight pre-transform (unchanged, verified).
// ---------------------------------------------------------------------------
__global__ __launch_bounds__(256) void wcvt_kernel(const float* __restrict__ W1,
        const float* __restrict__ W2, const float* __restrict__ W3,
        u16* __restrict__ w1h, u16* __restrict__ w1l,
        u16* __restrict__ w2h, u16* __restrict__ w2l,
        u16* __restrict__ w3h, u16* __restrict__ w3l) {
    int t = blockIdx.x * 256 + threadIdx.x;
    if (t < 64*KP1) {
        int n = t / KP1, k = t % KP1;
        u16 h, l; splitbf((k < FIN) ? W1[(long)k*HH + n] : 0.0f, h, l);
        w1h[t] = h; w1l[t] = l;
    }
    if (t < 64*64) {
        int n = t / 64, k = t % 64;
        u16 h, l; splitbf(W2[(long)k*HH + n], h, l);
        w2h[t] = h; w2l[t] = l;
    }
    if (t < 128*64) {
        int n = t / 64, k = t % 64;
        u16 h, l; splitbf(W3[(long)k*FOUT + n], h, l);
        w3h[t] = h; w3l[t] = l;
    }
}

// ---------------------------------------------------------------------------
// Kernel 2: fused radius + PointNetConv + max-pool, COLUMN-PARTITIONED waves.
// (unchanged, verified; absmax tripwire: exactly 0.015625)
// ---------------------------------------------------------------------------
__global__ __launch_bounds__(256) void conv_kernel(const float* __restrict__ x,
        const float* __restrict__ pos, const int* __restrict__ sel,
        const u16* __restrict__ w1h, const u16* __restrict__ w1l,
        const u16* __restrict__ w2h, const u16* __restrict__ w2l,
        const u16* __restrict__ w3h, const u16* __restrict__ w3l,
        const float* __restrict__ b1, const float* __restrict__ b2,
        const float* __restrict__ b3, float* __restrict__ xout) {
    __shared__ __align__(16) u16 fAh[64*SA], fAl[64*SA];   // feat, then h2 (stride S2)
    __shared__ __align__(16) u16 h1h[64*S2], h1l[64*S2];
    __shared__ float cdv[CAND_CAP];
    __shared__ int   cixv[CAND_CAP];
    __shared__ int   snbr[KNBR];
    __shared__ int   sc[2];
    const int c = blockIdx.x, t = threadIdx.x;
    const int b = c >> 11;
    const int lane = t & 63, w = t >> 6;
    const int colc = lane & 15;
    const float* pb = pos + (long)b * NPTS * 3;
    const int j0 = sel[c];
    const float qx = pb[j0*3+0], qy = pb[j0*3+1], qz = pb[j0*3+2];

    const int nw = w*16 + colc;            // this wave's column (layers 1-2)
    const float bias1 = b1[nw];
    const float bias2 = b2[nw];
    const float bias3[2] = { b3[(2*w+0)*16 + colc], b3[(2*w+1)*16 + colc] };

    if (t == 0) { sc[0] = 0; sc[1] = 0; }
    __syncthreads();

    // ---- radius gather (bit-exact; verified r4-r13)
    const float R2 = (float)(0.15 * 0.15);
    for (int it = 0; it < NPTS/256; ++it) {
        int i = t + 256*it;
        float dx = __fsub_rn(qx, pb[i*3+0]);
        float dy = __fsub_rn(qy, pb[i*3+1]);
        float dz = __fsub_rn(qz, pb[i*3+2]);
        float d2 = __fadd_rn(__fadd_rn(__fmul_rn(dx,dx), __fmul_rn(dy,dy)),
                             __fmul_rn(dz,dz));
        if (d2 <= R2) {
            int slot = atomicAdd(&sc[0], 1);
            if (slot < CAND_CAP) { cdv[slot] = d2; cixv[slot] = i; }
        }
    }
    __syncthreads();
    int C = sc[0]; if (C > CAND_CAP) C = CAND_CAP;
    int cnt;
    if (C <= KNBR) {
        for (int e = t; e < C; e += 256) snbr[e] = cixv[e];
        cnt = C;
    } else {
        for (int e = t; e < C; e += 256) {
            float de = cdv[e]; int ie = cixv[e];
            int rank = 0;
            for (int f = 0; f < C; ++f) {
                float df = cdv[f]; int jf = cixv[f];
                rank += (df < de || (df == de && jf < ie)) ? 1 : 0;
            }
            if (rank < KNBR) {
                int slot = atomicAdd(&sc[1], 1);
                snbr[slot] = ie;
            }
        }
        cnt = KNBR;
    }
    __syncthreads();

    // ---- stage features (4 threads/row); zero K-pad cols 67..99
    const int kk = t >> 2, sub = t & 3;
    if (kk < cnt) {
        int j = snbr[kk];
        const float4* xr4 = (const float4*)(x + ((long)b*NPTS + j) * FEAT);
        #pragma unroll
        for (int i = 0; i < 4; ++i) {
            int ci = sub*4 + i;
            float4 v = xr4[ci];
            u16 h0,l0,h1_,l1_,h2_,l2_,h3_,l3_;
            splitbf(v.x, h0, l0); splitbf(v.y, h1_, l1_);
            splitbf(v.z, h2_, l2_); splitbf(v.w, h3_, l3_);
            int o = kk*SA + ci*4;
            fAh[o+0]=h0; fAh[o+1]=h1_; fAh[o+2]=h2_; fAh[o+3]=h3_;
            fAl[o+0]=l0; fAl[o+1]=l1_; fAl[o+2]=l2_; fAl[o+3]=l3_;
        }
        if (sub < 3) {
            float qv = (sub == 0) ? qx : ((sub == 1) ? qy : qz);
            u16 h, l; splitbf(__fsub_rn(pb[j*3+sub], qv), h, l);
            fAh[kk*SA + 64 + sub] = h; fAl[kk*SA + 64 + sub] = l;
        } else {
            fAh[kk*SA + 67] = 0; fAl[kk*SA + 67] = 0;
        }
        u32* zh = (u32*)&fAh[kk*SA + 68];
        u32* zl = (u32*)&fAl[kk*SA + 68];
        #pragma unroll
        for (int i2 = 0; i2 < 4; ++i2) { zh[sub + 4*i2] = 0; zl[sub + 4*i2] = 0; }
    }
    __syncthreads();   // layer 1 reads ALL rows -> full barrier

    const int mL = lane & 15;              // A-row within a 16-row tile
    const int kq = (lane >> 4) * 8;
    const int rgrp = (lane >> 4) * 4;

    // ---- B-fragment loads: this wave's column stripe only (18 KB/wave)
    short8 B1h[3], B1l[3], B2h[2], B2l[2], B3h[2][2], B3l[2][2];
    #pragma unroll
    for (int i = 0; i < 3; ++i) {
        B1h[i] = *(const short8*)&w1h[nw*KP1 + i*32 + kq];
        B1l[i] = *(const short8*)&w1l[nw*KP1 + i*32 + kq];
    }
    #pragma unroll
    for (int i = 0; i < 2; ++i) {
        B2h[i] = *(const short8*)&w2h[nw*64 + i*32 + kq];
        B2l[i] = *(const short8*)&w2l[nw*64 + i*32 + kq];
    }

    // ---- layer 1: 96(67) -> 64, all 4 row-tiles, cols nw
    #pragma unroll
    for (int rt = 0; rt < 4; ++rt) {
        short8 ah[3], al[3];
        #pragma unroll
        for (int i = 0; i < 3; ++i) {
            ah[i] = *(const short8*)&fAh[(rt*16 + mL)*SA + i*32 + kq];
            al[i] = *(const short8*)&fAl[(rt*16 + mL)*SA + i*32 + kq];
        }
        f32x4 acc = {bias1, bias1, bias1, bias1};
        #pragma unroll
        for (int i = 0; i < 3; ++i)
            acc = __builtin_amdgcn_mfma_f32_16x16x32_bf16(ah[i], B1h[i], acc, 0,0,0);
        #pragma unroll
        for (int i = 0; i < 3; ++i)
            acc = __builtin_amdgcn_mfma_f32_16x16x32_bf16(ah[i], B1l[i], acc, 0,0,0);
        #pragma unroll
        for (int i = 0; i < 3; ++i)
            acc = __builtin_amdgcn_mfma_f32_16x16x32_bf16(al[i], B1h[i], acc, 0,0,0);
        #pragma unroll
        for (int r = 0; r < 4; ++r) {
            u16 h, l; splitbf(fmaxf(acc[r], 0.0f), h, l);
            int mr = rt*16 + rgrp + r;
            h1h[mr*S2 + nw] = h; h1l[mr*S2 + nw] = l;
        }
    }
    // prefetch layer-3 B while layer-1 results drain
    #pragma unroll
    for (int j = 0; j < 2; ++j) {
        int n3 = (2*w + j)*16 + colc;
        #pragma unroll
        for (int i = 0; i < 2; ++i) {
            B3h[j][i] = *(const short8*)&w3h[n3*64 + i*32 + kq];
            B3l[j][i] = *(const short8*)&w3l[n3*64 + i*32 + kq];
        }
    }
    __syncthreads();

    // ---- layer 2: 64 -> 64 (h2 overwrites fA, stride S2)
    #pragma unroll
    for (int rt = 0; rt < 4; ++rt) {
        short8 ah[2], al[2];
        #pragma unroll
        for (int i = 0; i < 2; ++i) {
            ah[i] = *(const short8*)&h1h[(rt*16 + mL)*S2 + i*32 + kq];
            al[i] = *(const short8*)&h1l[(rt*16 + mL)*S2 + i*32 + kq];
        }
        f32x4 acc = {bias2, bias2, bias2, bias2};
        #pragma unroll
        for (int i = 0; i < 2; ++i)
            acc = __builtin_amdgcn_mfma_f32_16x16x32_bf16(ah[i], B2h[i], acc, 0,0,0);
        #pragma unroll
        for (int i = 0; i < 2; ++i)
            acc = __builtin_amdgcn_mfma_f32_16x16x32_bf16(ah[i], B2l[i], acc, 0,0,0);
        #pragma unroll
        for (int i = 0; i < 2; ++i)
            acc = __builtin_amdgcn_mfma_f32_16x16x32_bf16(al[i], B2h[i], acc, 0,0,0);
        #pragma unroll
        for (int r = 0; r < 4; ++r) {
            u16 h, l; splitbf(fmaxf(acc[r], 0.0f), h, l);
            int mr = rt*16 + rgrp + r;
            fAh[mr*S2 + nw] = h; fAl[mr*S2 + nw] = l;
        }
    }
    __syncthreads();

    // ---- layer 3: 64 -> 128, 2 col stripes/wave, fused relu + masked pool
    #pragma unroll
    for (int j = 0; j < 2; ++j) {
        const float bb = bias3[j];
        float v = 0.0f;   // relu >= 0 and cnt >= 1 -> 0 is identity
        #pragma unroll
        for (int rt = 0; rt < 4; ++rt) {
            short8 ah[2], al[2];
            #pragma unroll
            for (int i = 0; i < 2; ++i) {
                ah[i] = *(const short8*)&fAh[(rt*16 + mL)*S2 + i*32 + kq];
                al[i] = *(const short8*)&fAl[(rt*16 + mL)*S2 + i*32 + kq];
            }
            f32x4 acc = {bb, bb, bb, bb};
            #pragma unroll
            for (int i = 0; i < 2; ++i)
                acc = __builtin_amdgcn_mfma_f32_16x16x32_bf16(ah[i], B3h[j][i], acc, 0,0,0);
            #pragma unroll
            for (int i = 0; i < 2; ++i)
                acc = __builtin_amdgcn_mfma_f32_16x16x32_bf16(ah[i], B3l[j][i], acc, 0,0,0);
            #pragma unroll
            for (int i = 0; i < 2; ++i)
                acc = __builtin_amdgcn_mfma_f32_16x16x32_bf16(al[i], B3h[j][i], acc, 0,0,0);
            #pragma unroll
            for (int r = 0; r < 4; ++r) {
                int m = rt*16 + rgrp + r;
                float hv = fmaxf(acc[r], 0.0f);
                v = (m < cnt) ? fmaxf(v, hv) : v;
            }
        }
        v = fmaxf(v, __shfl_xor(v, 16, 64));
        v = fmaxf(v, __shfl_xor(v, 32, 64));
        if (lane < 16)
            xout[(long)c*FOUT + (2*w + j)*16 + lane] = v;
    }
}

// ---------------------------------------------------------------------------
extern "C" void kernel_launch(void* const* d_in, const int* in_sizes, int n_in,
                              void* d_out, int out_size, void* d_ws, size_t ws_size,
                              hipStream_t stream) {
    const float* x   = (const float*)d_in[0];
    const float* pos = (const float*)d_in[1];
    const float* W1 = (const float*)d_in[3];
    const float* b1 = (const float*)d_in[4];
    const float* W2 = (const float*)d_in[5];
    const float* b2 = (const float*)d_in[6];
    const float* W3 = (const float*)d_in[7];
    const float* b3 = (const float*)d_in[8];

    float* out       = (float*)d_out;
    float* xout      = out;
    float* pos_out   = out + (long)NCENT * FOUT;
    float* batch_out = pos_out + (long)NCENT * 3;

    int* sel = (int*)d_ws;
    u16* w1h = (u16*)((char*)d_ws + 65536);
    u16* w1l = w1h + 64*KP1;
    u16* w2h = w1l + 64*KP1;
    u16* w2l = w2h + 64*64;
    u16* w3h = w2l + 64*64;
    u16* w3l = w3h + 128*64;

    wcvt_kernel<<<32, 256, 0, stream>>>(W1, W2, W3, w1h, w1l, w2h, w2l, w3h, w3l);
    fps_kernel<<<NB, 256, 0, stream>>>(pos, sel, pos_out, batch_out);
    conv_kernel<<<NCENT, 256, 0, stream>>>(x, pos, sel, w1h, w1l, w2h, w2l,
                                           w3h, w3l, b1, b2, b3, xout);
}

// Round 4
// 1999.990 us; speedup vs baseline: 1.4233x; 1.3728x over previous
//
#include <hip/hip_runtime.h>

typedef unsigned short u16;
typedef unsigned int u32;
typedef unsigned long long u64;

#define NB 8
#define NPTS 4096
#define MSEL 2048
#define NCENT (NB*MSEL)
#define KNBR 64
#define FEAT 64
#define FIN 67
#define HH 64
#define FOUT 128
#define CAND_CAP 192

#define KP1 96     // layer-1 K padded to 3x32
#define SA 104     // feat A-buffer row stride (bf16 elems)
#define S2 72      // h1/h2 row stride

typedef __attribute__((ext_vector_type(8))) short short8;
typedef __attribute__((ext_vector_type(4))) float f32x4;

__device__ __forceinline__ float bf2f(u16 u) {
    union { u32 i; float f; } v; v.i = ((u32)u) << 16; return v.f;
}
__device__ __forceinline__ u16 f2bf(float f) {
    union { float f; u32 i; } v; v.f = f;
    u32 x = v.i;
    x += 0x7fffu + ((x >> 16) & 1u);
    return (u16)(x >> 16);
}
__device__ __forceinline__ void splitbf(float a, u16& hi, u16& lo) {
    u16 h = f2bf(a);
    hi = h;
    lo = f2bf(__fsub_rn(a, bf2f(h)));
}

// ---------------------------------------------------------------------------
// DPP wave-64 reductions (verified r7-r13).
// ---------------------------------------------------------------------------
__device__ __forceinline__ int wave_max_i(int v) {
    int u;
    u = __builtin_amdgcn_update_dpp(v, v, 0x111, 0xf, 0xf, false); v = max(v, u);
    u = __builtin_amdgcn_update_dpp(v, v, 0x112, 0xf, 0xf, false); v = max(v, u);
    u = __builtin_amdgcn_update_dpp(v, v, 0x114, 0xf, 0xf, false); v = max(v, u);
    u = __builtin_amdgcn_update_dpp(v, v, 0x118, 0xf, 0xf, false); v = max(v, u);
    u = __builtin_amdgcn_update_dpp(v, v, 0x142, 0xf, 0xf, false); v = max(v, u);
    u = __builtin_amdgcn_update_dpp(v, v, 0x143, 0xf, 0xf, false); v = max(v, u);
    return __builtin_amdgcn_readlane(v, 63);
}
__device__ __forceinline__ int wave_min_i(int v) {
    int u;
    u = __builtin_amdgcn_update_dpp(v, v, 0x111, 0xf, 0xf, false); v = min(v, u);
    u = __builtin_amdgcn_update_dpp(v, v, 0x112, 0xf, 0xf, false); v = min(v, u);
    u = __builtin_amdgcn_update_dpp(v, v, 0x114, 0xf, 0xf, false); v = min(v, u);
    u = __builtin_amdgcn_update_dpp(v, v, 0x118, 0xf, 0xf, false); v = min(v, u);
    u = __builtin_amdgcn_update_dpp(v, v, 0x142, 0xf, 0xf, false); v = min(v, u);
    u = __builtin_amdgcn_update_dpp(v, v, 0x143, 0xf, 0xf, false); v = min(v, u);
    return __builtin_amdgcn_readlane(v, 63);
}

struct Cand { int M, I, xb, yb; };   // trivial POD (union-safe)

struct FpsSh {
    float px[NPTS], py[NPTS], pz[NPTS];
    int hist[MSEL];
    Cand sA[2][4];
    float sZ[2][4];
};
struct ConvSh {
    u16 fAh[64*SA], fAl[64*SA];   // feat, then h2 (stride S2)
    u16 h1h[64*S2], h1l[64*S2];
    float cdv[CAND_CAP];
    int   cixv[CAND_CAP];
    int   snbr[KNBR];
    int   sc[2];
};
union __align__(16) FusedSh { FpsSh f; ConvSh c; };

// ---------------------------------------------------------------------------
// Kernel 1.5: weight pre-transform (verified) + producer-consumer prog reset.
// Stream-ordered BEFORE the fused kernel => prog re-armed on every launch
// (incl. graph replay / rocprof replay).
// ---------------------------------------------------------------------------
__global__ __launch_bounds__(256) void wcvt_kernel(const float* __restrict__ W1,
        const float* __restrict__ W2, const float* __restrict__ W3,
        u16* __restrict__ w1h, u16* __restrict__ w1l,
        u16* __restrict__ w2h, u16* __restrict__ w2l,
        u16* __restrict__ w3h, u16* __restrict__ w3l,
        u32* __restrict__ prog) {
    int t = blockIdx.x * 256 + threadIdx.x;
    if (t < NB) prog[t] = 0;
    if (t < 64*KP1) {
        int n = t / KP1, k = t % KP1;
        u16 h, l; splitbf((k < FIN) ? W1[(long)k*HH + n] : 0.0f, h, l);
        w1h[t] = h; w1l[t] = l;
    }
    if (t < 64*64) {
        int n = t / 64, k = t % 64;
        u16 h, l; splitbf(W2[(long)k*HH + n], h, l);
        w2h[t] = h; w2l[t] = l;
    }
    if (t < 128*64) {
        int n = t / 64, k = t % 64;
        u16 h, l; splitbf(W3[(long)k*FOUT + n], h, l);
        w3h[t] = h; w3l[t] = l;
    }
}

// ---------------------------------------------------------------------------
// Fused kernel: blocks 0..7 = exact FPS (verbatim r13 body, measured 1618us)
// publishing selections progressively; blocks 8.. = conv (verbatim verified
// body) gated on the producer's progress counter. Handshake:
//   fps t0: batch of 16 sels -> relaxed agent stores; prog release LAGGED by
//           one batch (drain cost amortized to ~0); final release = MSEL.
//   conv t0: acquire-poll prog[b] >= (c&2047)+1 with s_sleep backoff; then
//           all threads agent-load sel[c]. Cross-XCD safe (per-XCD L2 not
//           coherent; sc-flagged atomic path bypasses stale lines).
// Forward progress: fps blocks are first in dispatch order and never wait.
// ---------------------------------------------------------------------------
__global__ __launch_bounds__(256) void fused_kernel(const float* __restrict__ x,
        const float* __restrict__ pos, int* __restrict__ sel,
        u32* __restrict__ prog,
        const u16* __restrict__ w1h, const u16* __restrict__ w1l,
        const u16* __restrict__ w2h, const u16* __restrict__ w2l,
        const u16* __restrict__ w3h, const u16* __restrict__ w3l,
        const float* __restrict__ b1, const float* __restrict__ b2,
        const float* __restrict__ b3, float* __restrict__ xout,
        float* __restrict__ pos_out, float* __restrict__ batch_out) {
    __shared__ FusedSh S;
    const int t = threadIdx.x;

    if (blockIdx.x < NB) {
        // =================== FPS role (r13-verbatim arithmetic) ===========
        const int b = blockIdx.x;
        const int wid = t >> 6;
        const float* pb = pos + (long)b * NPTS * 3;

        for (int i = t; i < NPTS; i += 256) {
            S.f.px[i] = pb[i*3+0]; S.f.py[i] = pb[i*3+1]; S.f.pz[i] = pb[i*3+2];
        }
        __syncthreads();

        float rx[16], ry[16], rz[16], md[16];
        #pragma unroll
        for (int j = 0; j < 16; ++j) {
            int i = t + 256*j;
            rx[j] = S.f.px[i]; ry[j] = S.f.py[i]; rz[j] = S.f.pz[i];
            md[j] = __builtin_inff();
        }

        int cur = 0;
        float cx = S.f.px[0], cy = S.f.py[0], cz = S.f.pz[0];
        for (int s = 0; s < MSEL; ++s) {
            const int p = s & 1;
            if (t == 0) {
                S.f.hist[s] = cur;
                if ((s & 15) == 15) {
                    if (s >= 16)   // release for PREVIOUS batch: drain is free
                        __hip_atomic_store(&prog[b], (u32)(s - 15),
                                           __ATOMIC_RELEASE, __HIP_MEMORY_SCOPE_AGENT);
                    #pragma unroll
                    for (int q = 0; q < 16; ++q) {
                        int ss = s - 15 + q;
                        __hip_atomic_store(&sel[(long)b*MSEL + ss], S.f.hist[ss],
                                           __ATOMIC_RELAXED, __HIP_MEMORY_SCOPE_AGENT);
                    }
                }
            }
            float bv = -1.0f; int bi = 0;
            #pragma unroll
            for (int j = 0; j < 16; ++j) {
                float dx = __fsub_rn(rx[j], cx);
                float dy = __fsub_rn(ry[j], cy);
                float dz = __fsub_rn(rz[j], cz);
                float d  = __fadd_rn(__fadd_rn(__fmul_rn(dx,dx), __fmul_rn(dy,dy)),
                                     __fmul_rn(dz,dz));
                float m = fminf(md[j], d);
                md[j] = m;
                if (m > bv) { bv = m; bi = t + 256*j; }   // strict >: first occurrence
            }
            const int fb = (int)__float_as_uint(bv);       // bv >= 0 -> int-ordered
            const int Mw = wave_max_i(fb);
            const int cnd = (fb == Mw) ? bi : 0x7fffffff;
            const int Iw = wave_min_i(cnd);                // wave argmax, min index
            if (t == (Iw & 255)) {                         // owner carries coords
                int j = Iw >> 8;
                Cand cc; cc.M = Mw; cc.I = Iw;
                cc.xb = __float_as_int(rx[j]); cc.yb = __float_as_int(ry[j]);
                S.f.sA[p][wid] = cc;
                S.f.sZ[p][wid] = rz[j];
            }
            __syncthreads();
            Cand v0 = S.f.sA[p][0];
            int M = v0.M, I = v0.I;
            float nx = __int_as_float(v0.xb), ny = __int_as_float(v0.yb);
            float nz = S.f.sZ[p][0];
            #pragma unroll
            for (int w2 = 1; w2 < 4; ++w2) {
                Cand vw = S.f.sA[p][w2];
                if (vw.M > M || (vw.M == M && vw.I < I)) {
                    M = vw.M; I = vw.I;
                    nx = __int_as_float(vw.xb); ny = __int_as_float(vw.yb);
                    nz = S.f.sZ[p][w2];
                }
            }
            cur = I; cx = nx; cy = ny; cz = nz;
        }
        __syncthreads();
        if (t == 0)   // final release: covers last batch (vmcnt drain, once)
            __hip_atomic_store(&prog[b], (u32)MSEL,
                               __ATOMIC_RELEASE, __HIP_MEMORY_SCOPE_AGENT);
        for (int g = t; g < MSEL; g += 256) {
            int i = S.f.hist[g];
            int o = b * MSEL + g;
            pos_out[o*3+0] = S.f.px[i]; pos_out[o*3+1] = S.f.py[i];
            pos_out[o*3+2] = S.f.pz[i];
            batch_out[o] = (float)b;
        }
        return;
    }

    // ====================== CONV role (verified body) =====================
    const int c = blockIdx.x - NB;
    const int b = c >> 11;
    const int lane = t & 63, w = t >> 6;
    const int colc = lane & 15;
    const float* pb = pos + (long)b * NPTS * 3;

    if (t == 0) {
        S.c.sc[0] = 0; S.c.sc[1] = 0;
        const u32 need = (u32)(c & (MSEL-1)) + 1u;
        while (__hip_atomic_load(&prog[b], __ATOMIC_ACQUIRE,
                                 __HIP_MEMORY_SCOPE_AGENT) < need)
            __builtin_amdgcn_s_sleep(16);
    }
    __syncthreads();
    const int j0 = (int)__hip_atomic_load(&sel[c], __ATOMIC_RELAXED,
                                          __HIP_MEMORY_SCOPE_AGENT);
    const float qx = pb[j0*3+0], qy = pb[j0*3+1], qz = pb[j0*3+2];

    const int nw = w*16 + colc;            // this wave's column (layers 1-2)
    const float bias1 = b1[nw];
    const float bias2 = b2[nw];
    const float bias3[2] = { b3[(2*w+0)*16 + colc], b3[(2*w+1)*16 + colc] };

    // ---- radius gather (bit-exact; verified r4-r13)
    const float R2 = (float)(0.15 * 0.15);
    for (int it = 0; it < NPTS/256; ++it) {
        int i = t + 256*it;
        float dx = __fsub_rn(qx, pb[i*3+0]);
        float dy = __fsub_rn(qy, pb[i*3+1]);
        float dz = __fsub_rn(qz, pb[i*3+2]);
        float d2 = __fadd_rn(__fadd_rn(__fmul_rn(dx,dx), __fmul_rn(dy,dy)),
                             __fmul_rn(dz,dz));
        if (d2 <= R2) {
            int slot = atomicAdd(&S.c.sc[0], 1);
            if (slot < CAND_CAP) { S.c.cdv[slot] = d2; S.c.cixv[slot] = i; }
        }
    }
    __syncthreads();
    int C = S.c.sc[0]; if (C > CAND_CAP) C = CAND_CAP;
    int cnt;
    if (C <= KNBR) {
        for (int e = t; e < C; e += 256) S.c.snbr[e] = S.c.cixv[e];
        cnt = C;
    } else {
        for (int e = t; e < C; e += 256) {
            float de = S.c.cdv[e]; int ie = S.c.cixv[e];
            int rank = 0;
            for (int f = 0; f < C; ++f) {
                float df = S.c.cdv[f]; int jf = S.c.cixv[f];
                rank += (df < de || (df == de && jf < ie)) ? 1 : 0;
            }
            if (rank < KNBR) {
                int slot = atomicAdd(&S.c.sc[1], 1);
                S.c.snbr[slot] = ie;
            }
        }
        cnt = KNBR;
    }
    __syncthreads();

    // ---- stage features (4 threads/row); zero K-pad cols 67..99
    const int kk = t >> 2, sub = t & 3;
    if (kk < cnt) {
        int j = S.c.snbr[kk];
        const float4* xr4 = (const float4*)(x + ((long)b*NPTS + j) * FEAT);
        #pragma unroll
        for (int i = 0; i < 4; ++i) {
            int ci = sub*4 + i;
            float4 v = xr4[ci];
            u16 h0,l0,h1_,l1_,h2_,l2_,h3_,l3_;
            splitbf(v.x, h0, l0); splitbf(v.y, h1_, l1_);
            splitbf(v.z, h2_, l2_); splitbf(v.w, h3_, l3_);
            int o = kk*SA + ci*4;
            S.c.fAh[o+0]=h0; S.c.fAh[o+1]=h1_; S.c.fAh[o+2]=h2_; S.c.fAh[o+3]=h3_;
            S.c.fAl[o+0]=l0; S.c.fAl[o+1]=l1_; S.c.fAl[o+2]=l2_; S.c.fAl[o+3]=l3_;
        }
        if (sub < 3) {
            float qv = (sub == 0) ? qx : ((sub == 1) ? qy : qz);
            u16 h, l; splitbf(__fsub_rn(pb[j*3+sub], qv), h, l);
            S.c.fAh[kk*SA + 64 + sub] = h; S.c.fAl[kk*SA + 64 + sub] = l;
        } else {
            S.c.fAh[kk*SA + 67] = 0; S.c.fAl[kk*SA + 67] = 0;
        }
        u32* zh = (u32*)&S.c.fAh[kk*SA + 68];
        u32* zl = (u32*)&S.c.fAl[kk*SA + 68];
        #pragma unroll
        for (int i2 = 0; i2 < 4; ++i2) { zh[sub + 4*i2] = 0; zl[sub + 4*i2] = 0; }
    }
    __syncthreads();   // layer 1 reads ALL rows -> full barrier

    const int mL = lane & 15;              // A-row within a 16-row tile
    const int kq = (lane >> 4) * 8;
    const int rgrp = (lane >> 4) * 4;

    // ---- B-fragment loads: this wave's column stripe only (18 KB/wave)
    short8 B1h[3], B1l[3], B2h[2], B2l[2], B3h[2][2], B3l[2][2];
    #pragma unroll
    for (int i = 0; i < 3; ++i) {
        B1h[i] = *(const short8*)&w1h[nw*KP1 + i*32 + kq];
        B1l[i] = *(const short8*)&w1l[nw*KP1 + i*32 + kq];
    }
    #pragma unroll
    for (int i = 0; i < 2; ++i) {
        B2h[i] = *(const short8*)&w2h[nw*64 + i*32 + kq];
        B2l[i] = *(const short8*)&w2l[nw*64 + i*32 + kq];
    }

    // ---- layer 1: 96(67) -> 64, all 4 row-tiles, cols nw
    #pragma unroll
    for (int rt = 0; rt < 4; ++rt) {
        short8 ah[3], al[3];
        #pragma unroll
        for (int i = 0; i < 3; ++i) {
            ah[i] = *(const short8*)&S.c.fAh[(rt*16 + mL)*SA + i*32 + kq];
            al[i] = *(const short8*)&S.c.fAl[(rt*16 + mL)*SA + i*32 + kq];
        }
        f32x4 acc = {bias1, bias1, bias1, bias1};
        #pragma unroll
        for (int i = 0; i < 3; ++i)
            acc = __builtin_amdgcn_mfma_f32_16x16x32_bf16(ah[i], B1h[i], acc, 0,0,0);
        #pragma unroll
        for (int i = 0; i < 3; ++i)
            acc = __builtin_amdgcn_mfma_f32_16x16x32_bf16(ah[i], B1l[i], acc, 0,0,0);
        #pragma unroll
        for (int i = 0; i < 3; ++i)
            acc = __builtin_amdgcn_mfma_f32_16x16x32_bf16(al[i], B1h[i], acc, 0,0,0);
        #pragma unroll
        for (int r = 0; r < 4; ++r) {
            u16 h, l; splitbf(fmaxf(acc[r], 0.0f), h, l);
            int mr = rt*16 + rgrp + r;
            S.c.h1h[mr*S2 + nw] = h; S.c.h1l[mr*S2 + nw] = l;
        }
    }
    // prefetch layer-3 B while layer-1 results drain
    #pragma unroll
    for (int j = 0; j < 2; ++j) {
        int n3 = (2*w + j)*16 + colc;
        #pragma unroll
        for (int i = 0; i < 2; ++i) {
            B3h[j][i] = *(const short8*)&w3h[n3*64 + i*32 + kq];
            B3l[j][i] = *(const short8*)&w3l[n3*64 + i*32 + kq];
        }
    }
    __syncthreads();

    // ---- layer 2: 64 -> 64 (h2 overwrites fA, stride S2)
    #pragma unroll
    for (int rt = 0; rt < 4; ++rt) {
        short8 ah[2], al[2];
        #pragma unroll
        for (int i = 0; i < 2; ++i) {
            ah[i] = *(const short8*)&S.c.h1h[(rt*16 + mL)*S2 + i*32 + kq];
            al[i] = *(const short8*)&S.c.h1l[(rt*16 + mL)*S2 + i*32 + kq];
        }
        f32x4 acc = {bias2, bias2, bias2, bias2};
        #pragma unroll
        for (int i = 0; i < 2; ++i)
            acc = __builtin_amdgcn_mfma_f32_16x16x32_bf16(ah[i], B2h[i], acc, 0,0,0);
        #pragma unroll
        for (int i = 0; i < 2; ++i)
            acc = __builtin_amdgcn_mfma_f32_16x16x32_bf16(ah[i], B2l[i], acc, 0,0,0);
        #pragma unroll
        for (int i = 0; i < 2; ++i)
            acc = __builtin_amdgcn_mfma_f32_16x16x32_bf16(al[i], B2h[i], acc, 0,0,0);
        #pragma unroll
        for (int r = 0; r < 4; ++r) {
            u16 h, l; splitbf(fmaxf(acc[r], 0.0f), h, l);
            int mr = rt*16 + rgrp + r;
            S.c.fAh[mr*S2 + nw] = h; S.c.fAl[mr*S2 + nw] = l;
        }
    }
    __syncthreads();

    // ---- layer 3: 64 -> 128, 2 col stripes/wave, fused relu + masked pool
    #pragma unroll
    for (int j = 0; j < 2; ++j) {
        const float bb = bias3[j];
        float v = 0.0f;   // relu >= 0 and cnt >= 1 -> 0 is identity
        #pragma unroll
        for (int rt = 0; rt < 4; ++rt) {
            short8 ah[2], al[2];
            #pragma unroll
            for (int i = 0; i < 2; ++i) {
                ah[i] = *(const short8*)&S.c.fAh[(rt*16 + mL)*S2 + i*32 + kq];
                al[i] = *(const short8*)&S.c.fAl[(rt*16 + mL)*S2 + i*32 + kq];
            }
            f32x4 acc = {bb, bb, bb, bb};
            #pragma unroll
            for (int i = 0; i < 2; ++i)
                acc = __builtin_amdgcn_mfma_f32_16x16x32_bf16(ah[i], B3h[j][i], acc, 0,0,0);
            #pragma unroll
            for (int i = 0; i < 2; ++i)
                acc = __builtin_amdgcn_mfma_f32_16x16x32_bf16(ah[i], B3l[j][i], acc, 0,0,0);
            #pragma unroll
            for (int i = 0; i < 2; ++i)
                acc = __builtin_amdgcn_mfma_f32_16x16x32_bf16(al[i], B3h[j][i], acc, 0,0,0);
            #pragma unroll
            for (int r = 0; r < 4; ++r) {
                int m = rt*16 + rgrp + r;
                float hv = fmaxf(acc[r], 0.0f);
                v = (m < cnt) ? fmaxf(v, hv) : v;
            }
        }
        v = fmaxf(v, __shfl_xor(v, 16, 64));
        v = fmaxf(v, __shfl_xor(v, 32, 64));
        if (lane < 16)
            xout[(long)c*FOUT + (2*w + j)*16 + lane] = v;
    }
}

// ---------------------------------------------------------------------------
extern "C" void kernel_launch(void* const* d_in, const int* in_sizes, int n_in,
                              void* d_out, int out_size, void* d_ws, size_t ws_size,
                              hipStream_t stream) {
    const float* x   = (const float*)d_in[0];
    const float* pos = (const float*)d_in[1];
    const float* W1 = (const float*)d_in[3];
    const float* b1 = (const float*)d_in[4];
    const float* W2 = (const float*)d_in[5];
    const float* b2 = (const float*)d_in[6];
    const float* W3 = (const float*)d_in[7];
    const float* b3 = (const float*)d_in[8];

    float* out       = (float*)d_out;
    float* xout      = out;
    float* pos_out   = out + (long)NCENT * FOUT;
    float* batch_out = pos_out + (long)NCENT * 3;

    int* sel = (int*)d_ws;
    u16* w1h = (u16*)((char*)d_ws + 65536);
    u16* w1l = w1h + 64*KP1;
    u16* w2h = w1l + 64*KP1;
    u16* w2l = w2h + 64*64;
    u16* w3h = w2l + 64*64;
    u16* w3l = w3h + 128*64;
    u32* prog = (u32*)(w3l + 128*64);

    wcvt_kernel<<<32, 256, 0, stream>>>(W1, W2, W3, w1h, w1l, w2h, w2l,
                                        w3h, w3l, prog);
    fused_kernel<<<NB + NCENT, 256, 0, stream>>>(x, pos, sel, prog,
                                                 w1h, w1l, w2h, w2l, w3h, w3l,
                                                 b1, b2, b3, xout, pos_out,
                                                 batch_out);
}

// Round 5
// 1735.742 us; speedup vs baseline: 1.6400x; 1.1522x over previous
//
#include <hip/hip_runtime.h>

typedef unsigned short u16;
typedef unsigned int u32;
typedef unsigned long long u64;

#define NB 8
#define NPTS 4096
#define MSEL 2048
#define NCENT (NB*MSEL)
#define KNBR 64
#define FEAT 64
#define FIN 67
#define HH 64
#define FOUT 128
#define CAND_CAP 192

#define KP1 96     // layer-1 K padded to 3x32
#define SA 104     // feat A-buffer row stride (bf16 elems)
#define S2 72      // h1/h2 row stride

typedef __attribute__((ext_vector_type(8))) short short8;
typedef __attribute__((ext_vector_type(4))) float f32x4;

__device__ __forceinline__ float bf2f(u16 u) {
    union { u32 i; float f; } v; v.i = ((u32)u) << 16; return v.f;
}
__device__ __forceinline__ u16 f2bf(float f) {
    union { float f; u32 i; } v; v.f = f;
    u32 x = v.i;
    x += 0x7fffu + ((x >> 16) & 1u);
    return (u16)(x >> 16);
}
__device__ __forceinline__ void splitbf(float a, u16& hi, u16& lo) {
    u16 h = f2bf(a);
    hi = h;
    lo = f2bf(__fsub_rn(a, bf2f(h)));
}

// ---------------------------------------------------------------------------
// DPP wave-64 reductions (verified r7-r13).
// ---------------------------------------------------------------------------
__device__ __forceinline__ int wave_max_i(int v) {
    int u;
    u = __builtin_amdgcn_update_dpp(v, v, 0x111, 0xf, 0xf, false); v = max(v, u);
    u = __builtin_amdgcn_update_dpp(v, v, 0x112, 0xf, 0xf, false); v = max(v, u);
    u = __builtin_amdgcn_update_dpp(v, v, 0x114, 0xf, 0xf, false); v = max(v, u);
    u = __builtin_amdgcn_update_dpp(v, v, 0x118, 0xf, 0xf, false); v = max(v, u);
    u = __builtin_amdgcn_update_dpp(v, v, 0x142, 0xf, 0xf, false); v = max(v, u);
    u = __builtin_amdgcn_update_dpp(v, v, 0x143, 0xf, 0xf, false); v = max(v, u);
    return __builtin_amdgcn_readlane(v, 63);
}
__device__ __forceinline__ int wave_min_i(int v) {
    int u;
    u = __builtin_amdgcn_update_dpp(v, v, 0x111, 0xf, 0xf, false); v = min(v, u);
    u = __builtin_amdgcn_update_dpp(v, v, 0x112, 0xf, 0xf, false); v = min(v, u);
    u = __builtin_amdgcn_update_dpp(v, v, 0x114, 0xf, 0xf, false); v = min(v, u);
    u = __builtin_amdgcn_update_dpp(v, v, 0x118, 0xf, 0xf, false); v = min(v, u);
    u = __builtin_amdgcn_update_dpp(v, v, 0x142, 0xf, 0xf, false); v = min(v, u);
    u = __builtin_amdgcn_update_dpp(v, v, 0x143, 0xf, 0xf, false); v = min(v, u);
    return __builtin_amdgcn_readlane(v, 63);
}

struct Cand { int M, I, xb, yb; };   // trivial POD (union-safe)

struct FpsSh {
    float px[NPTS], py[NPTS], pz[NPTS];
    int hist[MSEL];
    Cand sA[2][4];
    float sZ[2][4];
};
struct ConvSh {
    u16 fAh[64*SA], fAl[64*SA];   // feat, then h2 (stride S2)
    u16 h1h[64*S2], h1l[64*S2];
    float cdv[CAND_CAP];
    int   cixv[CAND_CAP];
    int   snbr[KNBR];
    int   sc[2];
};
// Pad to 84 KiB: 2x84KB > 160KB LDS/CU => exactly ONE block per CU. fps
// blocks get exclusive CUs (no issue-slot interference with the latency-
// critical argmax loop); conv at 1 blk/CU has ~3x the consumption capacity
// needed to track fps production, so no throughput loss where it matters.
union __align__(16) FusedSh { FpsSh f; ConvSh c; char pad[86016]; };

// ---------------------------------------------------------------------------
// Kernel 1.5: weight pre-transform (verified) + producer-consumer prog reset.
// Stream-ordered BEFORE the fused kernel => prog re-armed on every launch
// (incl. graph replay / rocprof replay).
// ---------------------------------------------------------------------------
__global__ __launch_bounds__(256) void wcvt_kernel(const float* __restrict__ W1,
        const float* __restrict__ W2, const float* __restrict__ W3,
        u16* __restrict__ w1h, u16* __restrict__ w1l,
        u16* __restrict__ w2h, u16* __restrict__ w2l,
        u16* __restrict__ w3h, u16* __restrict__ w3l,
        u32* __restrict__ prog) {
    int t = blockIdx.x * 256 + threadIdx.x;
    if (t < NB) prog[t] = 0;
    if (t < 64*KP1) {
        int n = t / KP1, k = t % KP1;
        u16 h, l; splitbf((k < FIN) ? W1[(long)k*HH + n] : 0.0f, h, l);
        w1h[t] = h; w1l[t] = l;
    }
    if (t < 64*64) {
        int n = t / 64, k = t % 64;
        u16 h, l; splitbf(W2[(long)k*HH + n], h, l);
        w2h[t] = h; w2l[t] = l;
    }
    if (t < 128*64) {
        int n = t / 64, k = t % 64;
        u16 h, l; splitbf(W3[(long)k*FOUT + n], h, l);
        w3h[t] = h; w3l[t] = l;
    }
}

// ---------------------------------------------------------------------------
// Fused kernel: blocks 0..7 = exact FPS (verbatim r13 body, measured 1618us)
// publishing selections progressively; blocks 8.. = conv (verbatim verified
// body) gated on the producer's progress counter.
//   conv block mapping is SEL-MAJOR: cb -> (b = cb&7, s = cb>>3), so the
//   resident window spans all 8 clouds at the same sel index and consumption
//   tracks production with ~30us lag (the r4 cloud-major mapping serialized
//   14k blocks after fps -- that was the +300us).
// Handshake (r4-verified): batched relaxed agent stores + lagged release;
// acquire-poll with s_sleep backoff; agent-scope load of sel (cross-XCD safe).
// Forward progress: fps blocks are first in dispatch order and never wait.
// ---------------------------------------------------------------------------
__global__ __launch_bounds__(256) void fused_kernel(const float* __restrict__ x,
        const float* __restrict__ pos, int* __restrict__ sel,
        u32* __restrict__ prog,
        const u16* __restrict__ w1h, const u16* __restrict__ w1l,
        const u16* __restrict__ w2h, const u16* __restrict__ w2l,
        const u16* __restrict__ w3h, const u16* __restrict__ w3l,
        const float* __restrict__ b1, const float* __restrict__ b2,
        const float* __restrict__ b3, float* __restrict__ xout,
        float* __restrict__ pos_out, float* __restrict__ batch_out) {
    __shared__ FusedSh S;
    const int t = threadIdx.x;

    if (blockIdx.x < NB) {
        // =================== FPS role (r13-verbatim arithmetic) ===========
        const int b = blockIdx.x;
        const int wid = t >> 6;
        const float* pb = pos + (long)b * NPTS * 3;

        for (int i = t; i < NPTS; i += 256) {
            S.f.px[i] = pb[i*3+0]; S.f.py[i] = pb[i*3+1]; S.f.pz[i] = pb[i*3+2];
        }
        __syncthreads();

        float rx[16], ry[16], rz[16], md[16];
        #pragma unroll
        for (int j = 0; j < 16; ++j) {
            int i = t + 256*j;
            rx[j] = S.f.px[i]; ry[j] = S.f.py[i]; rz[j] = S.f.pz[i];
            md[j] = __builtin_inff();
        }

        int cur = 0;
        float cx = S.f.px[0], cy = S.f.py[0], cz = S.f.pz[0];
        for (int s = 0; s < MSEL; ++s) {
            const int p = s & 1;
            if (t == 0) {
                S.f.hist[s] = cur;
                if ((s & 15) == 15) {
                    if (s >= 16)   // release for PREVIOUS batch: drain is free
                        __hip_atomic_store(&prog[b], (u32)(s - 15),
                                           __ATOMIC_RELEASE, __HIP_MEMORY_SCOPE_AGENT);
                    #pragma unroll
                    for (int q = 0; q < 16; ++q) {
                        int ss = s - 15 + q;
                        __hip_atomic_store(&sel[(long)b*MSEL + ss], S.f.hist[ss],
                                           __ATOMIC_RELAXED, __HIP_MEMORY_SCOPE_AGENT);
                    }
                }
            }
            float bv = -1.0f; int bi = 0;
            #pragma unroll
            for (int j = 0; j < 16; ++j) {
                float dx = __fsub_rn(rx[j], cx);
                float dy = __fsub_rn(ry[j], cy);
                float dz = __fsub_rn(rz[j], cz);
                float d  = __fadd_rn(__fadd_rn(__fmul_rn(dx,dx), __fmul_rn(dy,dy)),
                                     __fmul_rn(dz,dz));
                float m = fminf(md[j], d);
                md[j] = m;
                if (m > bv) { bv = m; bi = t + 256*j; }   // strict >: first occurrence
            }
            const int fb = (int)__float_as_uint(bv);       // bv >= 0 -> int-ordered
            const int Mw = wave_max_i(fb);
            const int cnd = (fb == Mw) ? bi : 0x7fffffff;
            const int Iw = wave_min_i(cnd);                // wave argmax, min index
            if (t == (Iw & 255)) {                         // owner carries coords
                int j = Iw >> 8;
                Cand cc; cc.M = Mw; cc.I = Iw;
                cc.xb = __float_as_int(rx[j]); cc.yb = __float_as_int(ry[j]);
                S.f.sA[p][wid] = cc;
                S.f.sZ[p][wid] = rz[j];
            }
            __syncthreads();
            Cand v0 = S.f.sA[p][0];
            int M = v0.M, I = v0.I;
            float nx = __int_as_float(v0.xb), ny = __int_as_float(v0.yb);
            float nz = S.f.sZ[p][0];
            #pragma unroll
            for (int w2 = 1; w2 < 4; ++w2) {
                Cand vw = S.f.sA[p][w2];
                if (vw.M > M || (vw.M == M && vw.I < I)) {
                    M = vw.M; I = vw.I;
                    nx = __int_as_float(vw.xb); ny = __int_as_float(vw.yb);
                    nz = S.f.sZ[p][w2];
                }
            }
            cur = I; cx = nx; cy = ny; cz = nz;
        }
        __syncthreads();
        if (t == 0)   // final release: covers last batch (vmcnt drain, once)
            __hip_atomic_store(&prog[b], (u32)MSEL,
                               __ATOMIC_RELEASE, __HIP_MEMORY_SCOPE_AGENT);
        for (int g = t; g < MSEL; g += 256) {
            int i = S.f.hist[g];
            int o = b * MSEL + g;
            pos_out[o*3+0] = S.f.px[i]; pos_out[o*3+1] = S.f.py[i];
            pos_out[o*3+2] = S.f.pz[i];
            batch_out[o] = (float)b;
        }
        return;
    }

    // ====================== CONV role (verified body) =====================
    const int cb = blockIdx.x - NB;
    const int b = cb & 7;                  // sel-major mapping
    const int s = cb >> 3;
    const int c = b * MSEL + s;
    const int lane = t & 63, w = t >> 6;
    const int colc = lane & 15;
    const float* pb = pos + (long)b * NPTS * 3;

    if (t == 0) {
        S.c.sc[0] = 0; S.c.sc[1] = 0;
        const u32 need = (u32)s + 1u;
        while (__hip_atomic_load(&prog[b], __ATOMIC_ACQUIRE,
                                 __HIP_MEMORY_SCOPE_AGENT) < need)
            __builtin_amdgcn_s_sleep(16);
    }
    __syncthreads();
    const int j0 = (int)__hip_atomic_load(&sel[c], __ATOMIC_RELAXED,
                                          __HIP_MEMORY_SCOPE_AGENT);
    const float qx = pb[j0*3+0], qy = pb[j0*3+1], qz = pb[j0*3+2];

    const int nw = w*16 + colc;            // this wave's column (layers 1-2)
    const float bias1 = b1[nw];
    const float bias2 = b2[nw];
    const float bias3[2] = { b3[(2*w+0)*16 + colc], b3[(2*w+1)*16 + colc] };

    // ---- radius gather (bit-exact; verified r4-r13)
    const float R2 = (float)(0.15 * 0.15);
    for (int it = 0; it < NPTS/256; ++it) {
        int i = t + 256*it;
        float dx = __fsub_rn(qx, pb[i*3+0]);
        float dy = __fsub_rn(qy, pb[i*3+1]);
        float dz = __fsub_rn(qz, pb[i*3+2]);
        float d2 = __fadd_rn(__fadd_rn(__fmul_rn(dx,dx), __fmul_rn(dy,dy)),
                             __fmul_rn(dz,dz));
        if (d2 <= R2) {
            int slot = atomicAdd(&S.c.sc[0], 1);
            if (slot < CAND_CAP) { S.c.cdv[slot] = d2; S.c.cixv[slot] = i; }
        }
    }
    __syncthreads();
    int C = S.c.sc[0]; if (C > CAND_CAP) C = CAND_CAP;
    int cnt;
    if (C <= KNBR) {
        for (int e = t; e < C; e += 256) S.c.snbr[e] = S.c.cixv[e];
        cnt = C;
    } else {
        for (int e = t; e < C; e += 256) {
            float de = S.c.cdv[e]; int ie = S.c.cixv[e];
            int rank = 0;
            for (int f = 0; f < C; ++f) {
                float df = S.c.cdv[f]; int jf = S.c.cixv[f];
                rank += (df < de || (df == de && jf < ie)) ? 1 : 0;
            }
            if (rank < KNBR) {
                int slot = atomicAdd(&S.c.sc[1], 1);
                S.c.snbr[slot] = ie;
            }
        }
        cnt = KNBR;
    }
    __syncthreads();

    // ---- stage features (4 threads/row); zero K-pad cols 67..99
    const int kk = t >> 2, sub = t & 3;
    if (kk < cnt) {
        int j = S.c.snbr[kk];
        const float4* xr4 = (const float4*)(x + ((long)b*NPTS + j) * FEAT);
        #pragma unroll
        for (int i = 0; i < 4; ++i) {
            int ci = sub*4 + i;
            float4 v = xr4[ci];
            u16 h0,l0,h1_,l1_,h2_,l2_,h3_,l3_;
            splitbf(v.x, h0, l0); splitbf(v.y, h1_, l1_);
            splitbf(v.z, h2_, l2_); splitbf(v.w, h3_, l3_);
            int o = kk*SA + ci*4;
            S.c.fAh[o+0]=h0; S.c.fAh[o+1]=h1_; S.c.fAh[o+2]=h2_; S.c.fAh[o+3]=h3_;
            S.c.fAl[o+0]=l0; S.c.fAl[o+1]=l1_; S.c.fAl[o+2]=l2_; S.c.fAl[o+3]=l3_;
        }
        if (sub < 3) {
            float qv = (sub == 0) ? qx : ((sub == 1) ? qy : qz);
            u16 h, l; splitbf(__fsub_rn(pb[j*3+sub], qv), h, l);
            S.c.fAh[kk*SA + 64 + sub] = h; S.c.fAl[kk*SA + 64 + sub] = l;
        } else {
            S.c.fAh[kk*SA + 67] = 0; S.c.fAl[kk*SA + 67] = 0;
        }
        u32* zh = (u32*)&S.c.fAh[kk*SA + 68];
        u32* zl = (u32*)&S.c.fAl[kk*SA + 68];
        #pragma unroll
        for (int i2 = 0; i2 < 4; ++i2) { zh[sub + 4*i2] = 0; zl[sub + 4*i2] = 0; }
    }
    __syncthreads();   // layer 1 reads ALL rows -> full barrier

    const int mL = lane & 15;              // A-row within a 16-row tile
    const int kq = (lane >> 4) * 8;
    const int rgrp = (lane >> 4) * 4;

    // ---- B-fragment loads: this wave's column stripe only (18 KB/wave)
    short8 B1h[3], B1l[3], B2h[2], B2l[2], B3h[2][2], B3l[2][2];
    #pragma unroll
    for (int i = 0; i < 3; ++i) {
        B1h[i] = *(const short8*)&w1h[nw*KP1 + i*32 + kq];
        B1l[i] = *(const short8*)&w1l[nw*KP1 + i*32 + kq];
    }
    #pragma unroll
    for (int i = 0; i < 2; ++i) {
        B2h[i] = *(const short8*)&w2h[nw*64 + i*32 + kq];
        B2l[i] = *(const short8*)&w2l[nw*64 + i*32 + kq];
    }

    // ---- layer 1: 96(67) -> 64, all 4 row-tiles, cols nw
    #pragma unroll
    for (int rt = 0; rt < 4; ++rt) {
        short8 ah[3], al[3];
        #pragma unroll
        for (int i = 0; i < 3; ++i) {
            ah[i] = *(const short8*)&S.c.fAh[(rt*16 + mL)*SA + i*32 + kq];
            al[i] = *(const short8*)&S.c.fAl[(rt*16 + mL)*SA + i*32 + kq];
        }
        f32x4 acc = {bias1, bias1, bias1, bias1};
        #pragma unroll
        for (int i = 0; i < 3; ++i)
            acc = __builtin_amdgcn_mfma_f32_16x16x32_bf16(ah[i], B1h[i], acc, 0,0,0);
        #pragma unroll
        for (int i = 0; i < 3; ++i)
            acc = __builtin_amdgcn_mfma_f32_16x16x32_bf16(ah[i], B1l[i], acc, 0,0,0);
        #pragma unroll
        for (int i = 0; i < 3; ++i)
            acc = __builtin_amdgcn_mfma_f32_16x16x32_bf16(al[i], B1h[i], acc, 0,0,0);
        #pragma unroll
        for (int r = 0; r < 4; ++r) {
            u16 h, l; splitbf(fmaxf(acc[r], 0.0f), h, l);
            int mr = rt*16 + rgrp + r;
            S.c.h1h[mr*S2 + nw] = h; S.c.h1l[mr*S2 + nw] = l;
        }
    }
    // prefetch layer-3 B while layer-1 results drain
    #pragma unroll
    for (int j = 0; j < 2; ++j) {
        int n3 = (2*w + j)*16 + colc;
        #pragma unroll
        for (int i = 0; i < 2; ++i) {
            B3h[j][i] = *(const short8*)&w3h[n3*64 + i*32 + kq];
            B3l[j][i] = *(const short8*)&w3l[n3*64 + i*32 + kq];
        }
    }
    __syncthreads();

    // ---- layer 2: 64 -> 64 (h2 overwrites fA, stride S2)
    #pragma unroll
    for (int rt = 0; rt < 4; ++rt) {
        short8 ah[2], al[2];
        #pragma unroll
        for (int i = 0; i < 2; ++i) {
            ah[i] = *(const short8*)&S.c.h1h[(rt*16 + mL)*S2 + i*32 + kq];
            al[i] = *(const short8*)&S.c.h1l[(rt*16 + mL)*S2 + i*32 + kq];
        }
        f32x4 acc = {bias2, bias2, bias2, bias2};
        #pragma unroll
        for (int i = 0; i < 2; ++i)
            acc = __builtin_amdgcn_mfma_f32_16x16x32_bf16(ah[i], B2h[i], acc, 0,0,0);
        #pragma unroll
        for (int i = 0; i < 2; ++i)
            acc = __builtin_amdgcn_mfma_f32_16x16x32_bf16(ah[i], B2l[i], acc, 0,0,0);
        #pragma unroll
        for (int i = 0; i < 2; ++i)
            acc = __builtin_amdgcn_mfma_f32_16x16x32_bf16(al[i], B2h[i], acc, 0,0,0);
        #pragma unroll
        for (int r = 0; r < 4; ++r) {
            u16 h, l; splitbf(fmaxf(acc[r], 0.0f), h, l);
            int mr = rt*16 + rgrp + r;
            S.c.fAh[mr*S2 + nw] = h; S.c.fAl[mr*S2 + nw] = l;
        }
    }
    __syncthreads();

    // ---- layer 3: 64 -> 128, 2 col stripes/wave, fused relu + masked pool
    #pragma unroll
    for (int j = 0; j < 2; ++j) {
        const float bb = bias3[j];
        float v = 0.0f;   // relu >= 0 and cnt >= 1 -> 0 is identity
        #pragma unroll
        for (int rt = 0; rt < 4; ++rt) {
            short8 ah[2], al[2];
            #pragma unroll
            for (int i = 0; i < 2; ++i) {
                ah[i] = *(const short8*)&S.c.fAh[(rt*16 + mL)*S2 + i*32 + kq];
                al[i] = *(const short8*)&S.c.fAl[(rt*16 + mL)*S2 + i*32 + kq];
            }
            f32x4 acc = {bb, bb, bb, bb};
            #pragma unroll
            for (int i = 0; i < 2; ++i)
                acc = __builtin_amdgcn_mfma_f32_16x16x32_bf16(ah[i], B3h[j][i], acc, 0,0,0);
            #pragma unroll
            for (int i = 0; i < 2; ++i)
                acc = __builtin_amdgcn_mfma_f32_16x16x32_bf16(ah[i], B3l[j][i], acc, 0,0,0);
            #pragma unroll
            for (int i = 0; i < 2; ++i)
                acc = __builtin_amdgcn_mfma_f32_16x16x32_bf16(al[i], B3h[j][i], acc, 0,0,0);
            #pragma unroll
            for (int r = 0; r < 4; ++r) {
                int m = rt*16 + rgrp + r;
                float hv = fmaxf(acc[r], 0.0f);
                v = (m < cnt) ? fmaxf(v, hv) : v;
            }
        }
        v = fmaxf(v, __shfl_xor(v, 16, 64));
        v = fmaxf(v, __shfl_xor(v, 32, 64));
        if (lane < 16)
            xout[(long)c*FOUT + (2*w + j)*16 + lane] = v;
    }
}

// ---------------------------------------------------------------------------
extern "C" void kernel_launch(void* const* d_in, const int* in_sizes, int n_in,
                              void* d_out, int out_size, void* d_ws, size_t ws_size,
                              hipStream_t stream) {
    const float* x   = (const float*)d_in[0];
    const float* pos = (const float*)d_in[1];
    const float* W1 = (const float*)d_in[3];
    const float* b1 = (const float*)d_in[4];
    const float* W2 = (const float*)d_in[5];
    const float* b2 = (const float*)d_in[6];
    const float* W3 = (const float*)d_in[7];
    const float* b3 = (const float*)d_in[8];

    float* out       = (float*)d_out;
    float* xout      = out;
    float* pos_out   = out + (long)NCENT * FOUT;
    float* batch_out = pos_out + (long)NCENT * 3;

    int* sel = (int*)d_ws;
    u16* w1h = (u16*)((char*)d_ws + 65536);
    u16* w1l = w1h + 64*KP1;
    u16* w2h = w1l + 64*KP1;
    u16* w2l = w2h + 64*64;
    u16* w3h = w2l + 64*64;
    u16* w3l = w3h + 128*64;
    u32* prog = (u32*)(w3l + 128*64);

    wcvt_kernel<<<32, 256, 0, stream>>>(W1, W2, W3, w1h, w1l, w2h, w2l,
                                        w3h, w3l, prog);
    fused_kernel<<<NB + NCENT, 256, 0, stream>>>(x, pos, sel, prog,
                                                 w1h, w1l, w2h, w2l, w3h, w3l,
                                                 b1, b2, b3, xout, pos_out,
                                                 batch_out);
}